// Round 2
// baseline (591.174 us; speedup 1.0000x reference)
//
#include <hip/hip_runtime.h>
#include <cstdint>
#include <cstddef>

typedef short s8vec __attribute__((ext_vector_type(8)));     // 8 bf16 (4 VGPRs)
typedef float f16acc __attribute__((ext_vector_type(16)));   // 16 fp32 acc

#define C_DIM 256
#define M_DIM 16384
#define BATCH 8
#define KSPLIT 32
#define KCHUNK 512
#define BK 64
#define LDSP 72   // padded LDS pitch in bf16 elems (0 bank conflicts measured)

static __device__ __forceinline__ unsigned short f2bf(float f) {
    union { float f; unsigned u; } v; v.f = f;
    unsigned r = v.u + 0x7fffu + ((v.u >> 16) & 1u);  // round-to-nearest-even
    return (unsigned short)(r >> 16);
}
static __device__ __forceinline__ float bf2f(unsigned short h) {
    union { unsigned u; float f; } v; v.u = ((unsigned)h) << 16;
    return v.f;
}

// ---------------------------------------------------------------------------
// cov partial, symmetric 3-tile: block computes one 128x128 quadrant of
// Xchunk @ Xchunk^T. tile 0:(0,0) 1:(1,1) 2:(1,0); (0,1) mirrored later.
// grid (3, KSPLIT, BATCH), 256 threads = 4 waves (2x2), 64x64 per wave.
// launch_bounds (256,4): VGPR was 108<=128, LDS 36.9KB*4<=160KB -> 4 blk/CU;
// previous (256,2) left the kernel latency-bound at 17% occupancy.
// ---------------------------------------------------------------------------
__global__ __launch_bounds__(256, 4)
void cov_kernel(const float* __restrict__ x, float* __restrict__ covraw,
                float* __restrict__ sums)
{
    __shared__ unsigned short As[128][LDSP];
    __shared__ unsigned short Bs[128][LDSP];
    const int tile = blockIdx.x;                  // 0,1,2
    const int kc   = blockIdx.y;
    const int b    = blockIdx.z;
    const int trow = (tile == 0) ? 0 : 128;
    const int tcol = (tile == 2) ? 0 : trow;
    const bool diag = (tile < 2);

    const int tid  = threadIdx.x;
    const int lane = tid & 63;
    const int wave = tid >> 6;      // 0..3
    const int wr = wave >> 1, wc = wave & 1;
    const int half = lane >> 5, l31 = lane & 31;

    const float* xb = x + (size_t)b * C_DIM * M_DIM + (size_t)kc * KCHUNK;

    f16acc acc[2][2] = {};
    float rowsum[8] = {0,0,0,0,0,0,0,0};
    const int sr = tid >> 4;          // 0..15
    const int sc = (tid & 15) * 4;    // 0..60

    // prologue: load kt=0
    float4 va[8], vb[8];
    {
        const float* sa = xb + (size_t)(trow + sr) * M_DIM + sc;
        #pragma unroll
        for (int i = 0; i < 8; ++i)
            va[i] = *(const float4*)(sa + (size_t)(16 * i) * M_DIM);
        if (!diag) {
            const float* sb2 = xb + (size_t)(tcol + sr) * M_DIM + sc;
            #pragma unroll
            for (int i = 0; i < 8; ++i)
                vb[i] = *(const float4*)(sb2 + (size_t)(16 * i) * M_DIM);
        }
    }

    const unsigned short (*Bp)[LDSP] = diag ? As : Bs;

    for (int kt = 0; kt < KCHUNK / BK; ++kt) {
        __syncthreads();   // previous kt's LDS consumers done
        #pragma unroll
        for (int i = 0; i < 8; ++i) {
            if (diag) rowsum[i] += va[i].x + va[i].y + va[i].z + va[i].w;
            ushort4 p;
            p.x = f2bf(va[i].x); p.y = f2bf(va[i].y);
            p.z = f2bf(va[i].z); p.w = f2bf(va[i].w);
            *(ushort4*)&As[sr + 16 * i][sc] = p;
        }
        if (!diag) {
            #pragma unroll
            for (int i = 0; i < 8; ++i) {
                ushort4 p;
                p.x = f2bf(vb[i].x); p.y = f2bf(vb[i].y);
                p.z = f2bf(vb[i].z); p.w = f2bf(vb[i].w);
                *(ushort4*)&Bs[sr + 16 * i][sc] = p;
            }
        }
        // prefetch next tile
        if (kt < KCHUNK / BK - 1) {
            const float* sa = xb + (size_t)(trow + sr) * M_DIM + (kt + 1) * BK + sc;
            #pragma unroll
            for (int i = 0; i < 8; ++i)
                va[i] = *(const float4*)(sa + (size_t)(16 * i) * M_DIM);
            if (!diag) {
                const float* sb2 = xb + (size_t)(tcol + sr) * M_DIM + (kt + 1) * BK + sc;
                #pragma unroll
                for (int i = 0; i < 8; ++i)
                    vb[i] = *(const float4*)(sb2 + (size_t)(16 * i) * M_DIM);
            }
        }
        __syncthreads();
        #pragma unroll
        for (int ks = 0; ks < 4; ++ks) {
            const int k0 = ks * 16 + half * 8;
            s8vec af[2], bfr[2];
            #pragma unroll
            for (int i = 0; i < 2; ++i)
                af[i] = *(const s8vec*)&As[wr * 64 + i * 32 + l31][k0];
            #pragma unroll
            for (int j = 0; j < 2; ++j)
                bfr[j] = *(const s8vec*)&Bp[wc * 64 + j * 32 + l31][k0];
            #pragma unroll
            for (int i = 0; i < 2; ++i)
                #pragma unroll
                for (int j = 0; j < 2; ++j)
                    acc[i][j] = __builtin_amdgcn_mfma_f32_32x32x16_bf16(
                        af[i], bfr[j], acc[i][j], 0, 0, 0);
        }
    }
    if (diag) {
        // 16 consecutive lanes share one staged row
        #pragma unroll
        for (int i = 0; i < 8; ++i) {
            float s = rowsum[i];
            s += __shfl_down(s, 8, 16);
            s += __shfl_down(s, 4, 16);
            s += __shfl_down(s, 2, 16);
            s += __shfl_down(s, 1, 16);
            if ((lane & 15) == 0)
                atomicAdd(&sums[b * C_DIM + trow + sr + 16 * i], s);
        }
    }
    float* covb = covraw + (size_t)b * C_DIM * C_DIM;
    #pragma unroll
    for (int i = 0; i < 2; ++i) {
        const int rb = trow + wr * 64 + i * 32 + 4 * half;
        #pragma unroll
        for (int j = 0; j < 2; ++j) {
            const int cb = tcol + wc * 64 + j * 32 + l31;
            #pragma unroll
            for (int r = 0; r < 16; ++r) {
                const int row = rb + (r & 3) + 8 * (r >> 2);
                atomicAdd(&covb[row * C_DIM + cb], acc[i][j][r]);
            }
        }
    }
}

// ---------------------------------------------------------------------------
// normsq + emit fused: one block per batch (1024 threads). Pass 1 computes
// ssq via block reduction (no atomics, no memset needed for it); pass 2
// emits Y0 = cov/normA (bf16) and T0 = 1.5I - 0.5 Y0 (== Z1, since Z0=I).
// ---------------------------------------------------------------------------
__global__ __launch_bounds__(1024)
void normsq_emit(const float* __restrict__ covraw, const float* __restrict__ sums,
                 float* __restrict__ normA_g,
                 unsigned short* __restrict__ Y0, unsigned short* __restrict__ T0)
{
    const int b = blockIdx.x;
    const int tid = threadIdx.x;
    const float invM = 1.0f / (float)M_DIM;
    const float* cb = covraw + (size_t)b * 65536;
    const float* sb = sums + b * 256;
    __shared__ float red[16];
    __shared__ float stot;

    float ss = 0.0f;
    #pragma unroll 4
    for (int i = 0; i < 64; ++i) {
        const int e = i * 1024 + tid;
        const int r = e >> 8, c = e & 255;
        const float raw = (r < 128 && c >= 128) ? cb[c * 256 + r] : cb[e];
        const float v = raw * invM - (sb[r] * invM) * (sb[c] * invM);
        ss += v * v;
    }
    #pragma unroll
    for (int off = 32; off; off >>= 1) ss += __shfl_down(ss, off, 64);
    if ((tid & 63) == 0) red[tid >> 6] = ss;
    __syncthreads();
    if (tid == 0) {
        float t = 0.0f;
        #pragma unroll
        for (int i = 0; i < 16; ++i) t += red[i];
        stot = t;
        normA_g[b] = sqrtf(t);
    }
    __syncthreads();
    const float inv = rsqrtf(stot);
    unsigned short* yb = Y0 + (size_t)b * 65536;
    unsigned short* tb = T0 + (size_t)b * 65536;
    #pragma unroll 4
    for (int i = 0; i < 64; ++i) {
        const int e = i * 1024 + tid;
        const int r = e >> 8, c = e & 255;
        const float raw = (r < 128 && c >= 128) ? cb[c * 256 + r] : cb[e];
        const float v = (raw * invM - (sb[r] * invM) * (sb[c] * invM)) * inv;
        yb[e] = f2bf(v);
        tb[e] = f2bf(((r == c) ? 1.5f : 0.0f) - 0.5f * v);
    }
}

// ---------------------------------------------------------------------------
// NS stage: C = c0*I + c1*(A @ B). All iterates symmetric => NT-gemm.
// 64x64 tiles: grid (16, BATCH, nprod), 256 threads (2x2 waves, 32x32 each)
// ---------------------------------------------------------------------------
__global__ __launch_bounds__(256, 4)
void ns_stage(const unsigned short* __restrict__ A0, const unsigned short* __restrict__ B0,
              unsigned short* __restrict__ C0,
              const unsigned short* __restrict__ A1, const unsigned short* __restrict__ B1,
              unsigned short* __restrict__ C1,
              float c0, float c1)
{
    __shared__ unsigned short As[64][LDSP];
    __shared__ unsigned short Bs[64][LDSP];
    const int b = blockIdx.y;
    const int trow = (blockIdx.x >> 2) * 64, tcol = (blockIdx.x & 3) * 64;
    const unsigned short* A = (blockIdx.z ? A1 : A0) + (size_t)b * 65536;
    const unsigned short* B = (blockIdx.z ? B1 : B0) + (size_t)b * 65536;
    unsigned short* Cp = (blockIdx.z ? C1 : C0) + (size_t)b * 65536;

    const int tid = threadIdx.x;
    const int lane = tid & 63, wave = tid >> 6;   // 0..3
    const int wr = wave >> 1, wc = wave & 1;
    const int half = lane >> 5, l31 = lane & 31;

    f16acc acc = {};

    const int sr = tid >> 3;        // 0..31
    const int sc = (tid & 7) * 8;   // 0..56
    for (int kt = 0; kt < 4; ++kt) {
        const int kb = kt * BK;
        uint4 va[2], vb[2];
        #pragma unroll
        for (int i = 0; i < 2; ++i) {
            va[i] = *(const uint4*)(A + (size_t)(trow + sr + 32 * i) * 256 + kb + sc);
            vb[i] = *(const uint4*)(B + (size_t)(tcol + sr + 32 * i) * 256 + kb + sc);
        }
        __syncthreads();
        #pragma unroll
        for (int i = 0; i < 2; ++i) {
            *(uint4*)&As[sr + 32 * i][sc] = va[i];
            *(uint4*)&Bs[sr + 32 * i][sc] = vb[i];
        }
        __syncthreads();
        #pragma unroll
        for (int ks = 0; ks < 4; ++ks) {
            const int k0 = ks * 16 + half * 8;
            s8vec af = *(const s8vec*)&As[wr * 32 + l31][k0];
            s8vec bfr = *(const s8vec*)&Bs[wc * 32 + l31][k0];
            acc = __builtin_amdgcn_mfma_f32_32x32x16_bf16(af, bfr, acc, 0, 0, 0);
        }
    }
    const int rb = trow + wr * 32 + 4 * half;
    const int cb = tcol + wc * 32 + l31;
    #pragma unroll
    for (int r = 0; r < 16; ++r) {
        const int row = rb + (r & 3) + 8 * (r >> 2);
        float v = c1 * acc[r] + ((row == cb) ? c0 : 0.0f);
        Cp[row * 256 + cb] = f2bf(v);
    }
}

// ---------------------------------------------------------------------------
// matvec chain: NS iterations 2..4 applied to vectors only.
// With Y2, Z2 materialized (bf16), define
//   T2(u) = 1.5u - 0.5 Z2 (Y2 u)
//   Y3(u) = Y2 (T2 u);  Z3(u) = T2 (Z2 u);  T3(u) = 1.5u - 0.5 Z3(Y3 u)
// then Z5@1 = 1.5 a - 0.5 e  with
//   s = Z3(1); a = T3(s); b = T3(a); c = Y3(b); d = Z3(c); e = T3(d)
// 27 fp32 matvecs (256^2 each) replace 6 GEMM dispatches, with LESS rounding
// than the old bf16 tail.
// ---------------------------------------------------------------------------
static __device__ __forceinline__ float mv256(const unsigned short* __restrict__ M,
                                              float xval, float* xs, int tid)
{
    xs[tid] = xval;
    __syncthreads();
    const unsigned short* mr = M + (size_t)tid * 256;
    float acc = 0.0f;
    #pragma unroll 4
    for (int i = 0; i < 32; ++i) {
        uint4 v = *(const uint4*)(mr + i * 8);
        const unsigned short* p = (const unsigned short*)&v;
        #pragma unroll
        for (int j = 0; j < 8; ++j) acc += bf2f(p[j]) * xs[i * 8 + j];
    }
    __syncthreads();   // xs free for next overwrite
    return acc;
}

struct MVCtx { const unsigned short* Y; const unsigned short* Z; float* xs; int tid; };

static __device__ __forceinline__ float T2ap(const MVCtx& m, float u) {
    float p = mv256(m.Y, u, m.xs, m.tid);
    float q = mv256(m.Z, p, m.xs, m.tid);
    return 1.5f * u - 0.5f * q;
}
static __device__ __forceinline__ float Y3ap(const MVCtx& m, float u) {
    return mv256(m.Y, T2ap(m, u), m.xs, m.tid);
}
static __device__ __forceinline__ float Z3ap(const MVCtx& m, float u) {
    return T2ap(m, mv256(m.Z, u, m.xs, m.tid));
}
static __device__ __forceinline__ float T3ap(const MVCtx& m, float u) {
    float w = Z3ap(m, Y3ap(m, u));
    return 1.5f * u - 0.5f * w;
}

// ---------------------------------------------------------------------------
// gating: matvec chain -> y -> h = relu(y@w1^T+b1) -> g = sigmoid(h@w2^T+b2)
// one block per batch, 256 threads (thread == matrix row).
// ---------------------------------------------------------------------------
__global__ __launch_bounds__(256)
void gating_kernel(const unsigned short* __restrict__ Y2, const unsigned short* __restrict__ Z2,
                   const float* __restrict__ normA_g,
                   const float* __restrict__ w1, const float* __restrict__ b1,
                   const float* __restrict__ w2, const float* __restrict__ b2,
                   float* __restrict__ g)
{
    const int b = blockIdx.x;
    const int tid = threadIdx.x;
    __shared__ float xs[256];
    __shared__ float sh[32];
    MVCtx m { Y2 + (size_t)b * 65536, Z2 + (size_t)b * 65536, xs, tid };

    float s  = Z3ap(m, 1.0f);
    float a  = T3ap(m, s);
    float bv = T3ap(m, a);
    float c  = Y3ap(m, bv);
    float d  = Z3ap(m, c);
    float e  = T3ap(m, d);

    const float y = (1.5f * a - 0.5f * e) * (1.0f / 256.0f) / sqrtf(normA_g[b]);
    xs[tid] = y;           // T3ap ended with __syncthreads -> safe to overwrite
    __syncthreads();
    if (tid < 32) {
        float hh = b1[tid];
        const float* w1r = w1 + tid * 256;
        for (int c2 = 0; c2 < 256; ++c2) hh += w1r[c2] * xs[c2];
        sh[tid] = hh > 0.0f ? hh : 0.0f;
    }
    __syncthreads();
    float z = b2[tid];
    const float* w2r = w2 + tid * 32;
    #pragma unroll
    for (int j = 0; j < 32; ++j) z += w2r[j] * sh[j];
    g[b * 256 + tid] = 1.0f / (1.0f + expf(-z));
}

// ---------------------------------------------------------------------------
// scale: out = x * g[b,c]
// ---------------------------------------------------------------------------
__global__ __launch_bounds__(256)
void scale_kernel(const float* __restrict__ x, const float* __restrict__ g,
                  float* __restrict__ out)
{
    const float4* x4 = (const float4*)x;
    float4* o4 = (float4*)out;
    #pragma unroll
    for (int it = 0; it < 4; ++it) {
        size_t i = (size_t)blockIdx.x * 1024 + it * 256 + threadIdx.x;
        float gg = g[i >> 12];
        float4 v = x4[i];
        float4 r;
        r.x = v.x * gg; r.y = v.y * gg; r.z = v.z * gg; r.w = v.w * gg;
        o4[i] = r;
    }
}

extern "C" void kernel_launch(void* const* d_in, const int* in_sizes, int n_in,
                              void* d_out, int out_size, void* d_ws, size_t ws_size,
                              hipStream_t stream)
{
    const float* x  = (const float*)d_in[0];
    const float* w1 = (const float*)d_in[1];
    const float* b1 = (const float*)d_in[2];
    const float* w2 = (const float*)d_in[3];
    const float* b2 = (const float*)d_in[4];
    float* out = (float*)d_out;

    char* ws = (char*)d_ws;
    float* covraw = (float*)ws;                        // 2 MB fp32
    float* sums   = (float*)(ws + 2097152);            // 8 KB
    float* normA  = (float*)(ws + 2105600);            // 32 B
    float* g      = (float*)(ws + 2106368);            // 8 KB
    unsigned short* Ya = (unsigned short*)(ws + 4194304);
    unsigned short* Yb = (unsigned short*)(ws + 5242880);
    unsigned short* Za = (unsigned short*)(ws + 6291456);
    unsigned short* Zb = (unsigned short*)(ws + 7340032);
    unsigned short* Tm = (unsigned short*)(ws + 8388608);  // 1 MB, total 9.44 MB

    hipMemsetAsync(covraw, 0, 2105344, stream);  // covraw + sums

    cov_kernel<<<dim3(3, KSPLIT, BATCH), 256, 0, stream>>>(x, covraw, sums);

    // Y0 -> Ya, T0 (== Z1) -> Za, normA
    normsq_emit<<<BATCH, 1024, 0, stream>>>(covraw, sums, normA, Ya, Za);

    // Y1 = Y0 @ T0
    ns_stage<<<dim3(16, BATCH, 1), 256, 0, stream>>>(Ya, Za, Yb, Ya, Za, Yb, 0.0f, 1.0f);
    // T1 = 1.5 I - 0.5 * Z1 @ Y1
    ns_stage<<<dim3(16, BATCH, 1), 256, 0, stream>>>(Za, Yb, Tm, Za, Yb, Tm, 1.5f, -0.5f);
    // Y2 = Y1 @ T1 ; Z2 = T1 @ Z1
    ns_stage<<<dim3(16, BATCH, 2), 256, 0, stream>>>(Yb, Tm, Ya, Tm, Za, Zb, 0.0f, 1.0f);

    // NS iters 2..4 collapse to 27 matvecs inside gating (Y2 = Ya, Z2 = Zb)
    gating_kernel<<<BATCH, 256, 0, stream>>>(Ya, Zb, normA, w1, b1, w2, b2, g);
    scale_kernel<<<8192, 256, 0, stream>>>(x, g, out);
}